// Round 7
// baseline (96.270 us; speedup 1.0000x reference)
//
#include <hip/hip_runtime.h>
#include <math.h>

// Problem constants: B=64, D=512, H=W=32 -> N=1024, NH=8, DH=64
#define BATCH  64
#define DCH    512
#define NPOS   1024
#define NH     8
#define NSPLIT 32
#define NRANGE 32      // NPOS / NSPLIT

// ---------------------------------------------------------------------------
// K1 (prep): blocks 0-1: wqT[c*8+h] = 0.125 * sum_d q[h,d]*Wkv[c,h*64+d]
//            blocks 2-5: bias[h*1024+n] = 0.125*(q.pe[n] + q.bkv)
// ---------------------------------------------------------------------------
__global__ __launch_bounds__(256) void k_prep(const float* __restrict__ q,
                                              const float* __restrict__ Wkv,
                                              const float* __restrict__ bkv,
                                              float* __restrict__ wqT,
                                              float* __restrict__ bias) {
    int blk = blockIdx.x;
    if (blk < 2) {
        int c = blk * 256 + threadIdx.x;
        const float4* wrow = (const float4*)(Wkv + (size_t)c * (2 * DCH));
        const float4* q4   = (const float4*)q;
        #pragma unroll
        for (int h = 0; h < NH; ++h) {
            float s = 0.f;
            #pragma unroll
            for (int d4 = 0; d4 < 16; ++d4) {
                float4 a = q4[h * 16 + d4];
                float4 w = wrow[h * 16 + d4];
                s = fmaf(a.x, w.x, fmaf(a.y, w.y, fmaf(a.z, w.z, fmaf(a.w, w.w, s))));
            }
            wqT[c * NH + h] = 0.125f * s;
        }
    } else {
        int n = (blk - 2) * 256 + threadIdx.x;
        float pq[NH];
        #pragma unroll
        for (int h = 0; h < NH; ++h) pq[h] = 0.f;
        const float kfac2 = -13.2877123795494f / 64.f;   // -log2(10000)/64
        for (int i = 0; i < 32; ++i) {
            float dt = exp2f((float)(2 * i) * kfac2);
            float ang = (float)n * dt;
            float sn, cs;
            sincosf(ang, &sn, &cs);
            #pragma unroll
            for (int h = 0; h < NH; ++h)
                pq[h] = fmaf(q[h * 64 + 2 * i], sn,
                        fmaf(q[h * 64 + 2 * i + 1], cs, pq[h]));
        }
        #pragma unroll
        for (int h = 0; h < NH; ++h) {
            float bq = 0.f;
            #pragma unroll 8
            for (int d = 0; d < 64; ++d)
                bq = fmaf(q[h * 64 + d], bkv[h * 64 + d], bq);
            bias[h * NPOS + n] = 0.125f * (pq[h] + bq);
        }
    }
}

// ---------------------------------------------------------------------------
// K2 (flash): grid (NSPLIT=32, B) = 2048 blocks, 512 threads, 2 blocks/CU.
// x tile (512 c x 32 n, 64 KB) is read from HBM exactly ONCE into registers,
// consumed for the dots, and ds_written (granule-XOR swizzled) for phase 3.
//  phase 1: lane=(rg=l>>3, n8=l&7); 8 float4 global loads in flight; wq from
//           LDS (broadcast reads); reduce over rg via xor8/16/32.
//  phase 2: wave h = head h, lanes 0-31, in-wave softmax over 32 n.
//  phase 3: lane=(rg16=l>>2, nq=l&3); x from LDS tile (swizzle-read),
//           p broadcast from LDS; quad-reduce xor1/xor2; coalesced stores.
// LDS: tile 64 KB + aux 16 KB (wqs, overlaid later by sred 8 KB + pbuf 1 KB)
// ---------------------------------------------------------------------------
__global__ __launch_bounds__(512) void k_flash(const float* __restrict__ x,
                                               const float* __restrict__ wqT,
                                               const float* __restrict__ bias,
                                               float* __restrict__ apart,  // [NSPLIT][B][NH][DCH]
                                               float* __restrict__ mz) {   // [NSPLIT][B][16]
    __shared__ float tile[DCH * NRANGE];   // 64 KB, swizzled granules
    __shared__ float aux[4096];            // 16 KB: wqs -> (sred | pbuf)

    int b = blockIdx.y, ns = blockIdx.x;
    int t = threadIdx.x;
    int w = t >> 6;
    int lane = t & 63;
    int n0 = ns * NRANGE;
    int c0 = w * 64;

    // stage wq -> aux (16 KB, coalesced)
    {
        const float4* src = (const float4*)wqT;
        float4* dst = (float4*)aux;
        dst[t]       = src[t];
        dst[t + 512] = src[t + 512];
    }
    __syncthreads();

    // ---------------- phase 1: load x once, dots, stage tile ----------------
    int rg = lane >> 3;     // 8 row-groups
    int n8 = lane & 7;      // 8 n-quads
    {
        const float* gx = x + ((size_t)b * DCH + c0 + rg) * NPOS + n0 + n8 * 4;
        float4 xv[8];
        #pragma unroll
        for (int k = 0; k < 8; ++k)
            xv[k] = *(const float4*)(gx + (size_t)(8 * k) * NPOS);

        float acc[NH][4];
        #pragma unroll
        for (int h = 0; h < NH; ++h)
            #pragma unroll
            for (int e = 0; e < 4; ++e) acc[h][e] = 0.f;

        #pragma unroll
        for (int k = 0; k < 8; ++k) {
            int c = c0 + 8 * k + rg;
            // swizzled stage: granule slot = n8 ^ (c&7); c&7 == rg
            *(float4*)&tile[c * NRANGE + ((n8 ^ rg) << 2)] = xv[k];
            float wv[8];
            *(float4*)&wv[0] = *(const float4*)&aux[c * 8];
            *(float4*)&wv[4] = *(const float4*)&aux[c * 8 + 4];
            #pragma unroll
            for (int h = 0; h < NH; ++h) {
                acc[h][0] = fmaf(xv[k].x, wv[h], acc[h][0]);
                acc[h][1] = fmaf(xv[k].y, wv[h], acc[h][1]);
                acc[h][2] = fmaf(xv[k].z, wv[h], acc[h][2]);
                acc[h][3] = fmaf(xv[k].w, wv[h], acc[h][3]);
            }
        }
        // reduce across the 8 row-groups (lane bits 3,4,5)
        #pragma unroll
        for (int h = 0; h < NH; ++h)
            #pragma unroll
            for (int e = 0; e < 4; ++e) {
                float v = acc[h][e];
                v += __shfl_xor(v, 8);
                v += __shfl_xor(v, 16);
                v += __shfl_xor(v, 32);
                acc[h][e] = v;
            }
        __syncthreads();   // all wqs reads done; aux can be overlaid
        if (rg == 0) {
            #pragma unroll
            for (int h = 0; h < NH; ++h)
                *(float4*)&aux[(w * NH + h) * NRANGE + n8 * 4] =   // sred
                    make_float4(acc[h][0], acc[h][1], acc[h][2], acc[h][3]);
        }
    }
    __syncthreads();

    // ---------------- phase 2: softmax (wave w = head w, lanes 0-31) --------
    if (lane < 32) {
        int h = w;
        int n = lane;
        float s = bias[h * NPOS + n0 + n];
        #pragma unroll
        for (int o = 0; o < 8; ++o) s += aux[(o * NH + h) * NRANGE + n];
        float m = s;
        #pragma unroll
        for (int o = 16; o; o >>= 1) m = fmaxf(m, __shfl_xor(m, o));
        float p = expf(s - m);
        float z = p;
        #pragma unroll
        for (int o = 16; o; o >>= 1) z += __shfl_xor(z, o);
        aux[2048 + h * NRANGE + n] = p;    // pbuf
        if (lane == 0) {
            float* mzp = mz + ((size_t)ns * BATCH + b) * 2 * NH;
            mzp[h]      = m;
            mzp[NH + h] = z;
        }
    }
    __syncthreads();

    // ---------------- phase 3: a[h][c] from LDS tile ----------------
    {
        int rg16 = lane >> 2;   // 16 rows per p-step
        int nq   = lane & 3;    // 4 n-quads; 8 n per thread (j=0,1)

        float con[4][NH];
        #pragma unroll
        for (int p = 0; p < 4; ++p)
            #pragma unroll
            for (int h = 0; h < NH; ++h) con[p][h] = 0.f;

        #pragma unroll
        for (int j = 0; j < 2; ++j) {
            float4 pj[NH];
            #pragma unroll
            for (int h = 0; h < NH; ++h)
                pj[h] = *(const float4*)&aux[2048 + h * NRANGE + nq * 4 + j * 16];
            #pragma unroll
            for (int p = 0; p < 4; ++p) {
                int c = c0 + p * 16 + rg16;
                int g = (nq + 4 * j) ^ (rg16 & 7);
                float4 xr = *(const float4*)&tile[c * NRANGE + g * 4];
                #pragma unroll
                for (int h = 0; h < NH; ++h)
                    con[p][h] = fmaf(xr.x, pj[h].x, fmaf(xr.y, pj[h].y,
                                fmaf(xr.z, pj[h].z, fmaf(xr.w, pj[h].w, con[p][h]))));
            }
        }

        // reduce over nq (xor1, xor2 — quad_perm DPP)
        #pragma unroll
        for (int p = 0; p < 4; ++p)
            #pragma unroll
            for (int h = 0; h < NH; ++h) {
                float v = con[p][h];
                v += __shfl_xor(v, 1);
                v += __shfl_xor(v, 2);
                con[p][h] = v;
            }

        size_t abase = ((size_t)ns * BATCH + b) * (NH * DCH);
        #pragma unroll
        for (int p = 0; p < 4; ++p) {
            int c = c0 + p * 16 + rg16;
            float lo = (nq == 0) ? con[p][0] : (nq == 1) ? con[p][1]
                     : (nq == 2) ? con[p][2] : con[p][3];
            float hi = (nq == 0) ? con[p][4] : (nq == 1) ? con[p][5]
                     : (nq == 2) ? con[p][6] : con[p][7];
            apart[abase + (size_t)nq * DCH + c]       = lo;
            apart[abase + (size_t)(nq + 4) * DCH + c] = hi;
        }
    }
}

// ---------------------------------------------------------------------------
// K3: combine 32 partials + output GEMV. grid (B, 2), 512 threads.
// ---------------------------------------------------------------------------
__global__ __launch_bounds__(512) void k_comb(const float* __restrict__ apart,
                                              const float* __restrict__ mz,
                                              const float* __restrict__ Wkv,
                                              const float* __restrict__ bkv,
                                              float* __restrict__ out) {
    __shared__ float as[NH * DCH];
    __shared__ float red[2][256];
    int b = blockIdx.x, half = blockIdx.y, t = threadIdx.x;
    int h = t >> 6;

    float M = -1e30f;
    #pragma unroll
    for (int j = 0; j < NSPLIT; ++j)
        M = fmaxf(M, mz[((size_t)j * BATCH + b) * 2 * NH + h]);
    float Z = 0.f, fj[NSPLIT];
    #pragma unroll
    for (int j = 0; j < NSPLIT; ++j) {
        const float* mzp = mz + ((size_t)j * BATCH + b) * 2 * NH;
        fj[j] = expf(mzp[h] - M);
        Z = fmaf(fj[j], mzp[NH + h], Z);
    }
    float invZ = 1.f / Z;

    int e0 = t * 8;
    float v[8];
    #pragma unroll
    for (int k = 0; k < 8; ++k) v[k] = 0.f;
    #pragma unroll 4
    for (int j = 0; j < NSPLIT; ++j) {
        const float* src = apart + ((size_t)j * BATCH + b) * (NH * DCH) + e0;
        float4 lo = *(const float4*)(src);
        float4 hi = *(const float4*)(src + 4);
        v[0] = fmaf(fj[j], lo.x, v[0]);
        v[1] = fmaf(fj[j], lo.y, v[1]);
        v[2] = fmaf(fj[j], lo.z, v[2]);
        v[3] = fmaf(fj[j], lo.w, v[3]);
        v[4] = fmaf(fj[j], hi.x, v[4]);
        v[5] = fmaf(fj[j], hi.y, v[5]);
        v[6] = fmaf(fj[j], hi.z, v[6]);
        v[7] = fmaf(fj[j], hi.w, v[7]);
    }
    #pragma unroll
    for (int k = 0; k < 8; ++k) as[e0 + k] = v[k] * invZ;
    __syncthreads();

    int o  = t & 255;
    int cp = t >> 8;
    int hd = half * 256 + o;
    int ho = hd >> 6;
    float a0 = 0.f, a1 = 0.f, a2 = 0.f, a3 = 0.f;
    const float* wp  = Wkv + DCH + hd;
    const float* apr = as + ho * DCH;
    int cbeg = cp * 256;
    #pragma unroll 4
    for (int c = cbeg; c < cbeg + 256; c += 4) {
        a0 = fmaf(apr[c],     wp[(size_t)c * (2 * DCH)],       a0);
        a1 = fmaf(apr[c + 1], wp[(size_t)(c + 1) * (2 * DCH)], a1);
        a2 = fmaf(apr[c + 2], wp[(size_t)(c + 2) * (2 * DCH)], a2);
        a3 = fmaf(apr[c + 3], wp[(size_t)(c + 3) * (2 * DCH)], a3);
    }
    red[cp][o] = (a0 + a1) + (a2 + a3);
    __syncthreads();
    if (t < 256) {
        int hd2 = half * 256 + t;
        out[(size_t)b * DCH + hd2] = bkv[DCH + hd2] + red[0][t] + red[1][t];
    }
}

// ---------------------------------------------------------------------------
extern "C" void kernel_launch(void* const* d_in, const int* in_sizes, int n_in,
                              void* d_out, int out_size, void* d_ws, size_t ws_size,
                              hipStream_t stream) {
    const float* x   = (const float*)d_in[0];   // (64, 512, 32, 32)
    const float* q   = (const float*)d_in[1];   // (1, 8, 1, 64)
    const float* Wkv = (const float*)d_in[2];   // (512, 1024)
    const float* bkv = (const float*)d_in[3];   // (1024,)
    float* out = (float*)d_out;                 // (64, 512)

    float* ws    = (float*)d_ws;
    float* wqT   = ws;                                         // 512*8
    float* bias  = wqT + DCH * NH;                             // 8*1024
    float* apart = bias + NH * NPOS;                           // 32 MiB
    float* mz    = apart + (size_t)NSPLIT * BATCH * NH * DCH;  // 32*64*16

    hipLaunchKernelGGL(k_prep,  dim3(6),             dim3(256), 0, stream, q, Wkv, bkv, wqT, bias);
    hipLaunchKernelGGL(k_flash, dim3(NSPLIT, BATCH), dim3(512), 0, stream, x, wqT, bias, apart, mz);
    hipLaunchKernelGGL(k_comb,  dim3(BATCH, 2),      dim3(512), 0, stream, apart, mz, Wkv, bkv, out);
}